// Round 3
// baseline (1615.754 us; speedup 1.0000x reference)
//
#include <hip/hip_runtime.h>

#define DEVI __device__ __forceinline__

typedef __bf16 bf16x8 __attribute__((ext_vector_type(8)));
typedef float  f32x4  __attribute__((ext_vector_type(4)));

static constexpr int Bb = 8, Tt = 24, Nn = 96, Dd = 32;
static constexpr int TO = 23;                 // output timesteps (outs[:-1])
static constexpr int TB = TO * Bb;            // 184 (t,b) groups
static constexpr int ROWS = TB * Nn;          // 17664 (t,b,i) rows

DEVI unsigned short f2bf(float f) {
  union { float f; unsigned u; } v; v.f = f;
  unsigned r = v.u + 0x7FFFu + ((v.u >> 16) & 1u);  // RNE
  return (unsigned short)(r >> 16);
}
DEVI float bf2f(unsigned short u) {
  union { unsigned u; float f; } v; v.u = (unsigned)u << 16; return v.f;
}

// ---------- pack f32 weights -> bf16 MFMA B-fragment layout ----------
// dst[((kb*NB+nb)*64+lane)*8+j] = W[kb*32+(lane>>4)*8+j][nb*16+(lane&15)]
__global__ void pack_kernel(const float* __restrict__ W, unsigned short* __restrict__ dst,
                            int K, int N) {
  int p = blockIdx.x * 256 + threadIdx.x;
  if (p >= K * N) return;
  int j = p & 7, lane = (p >> 3) & 63, pb = p >> 9;
  int NB = N >> 4;
  int nb = pb % NB, kb = pb / NB;
  int k = kb * 32 + ((lane >> 4) << 3) + j;
  int n = nb * 16 + (lane & 15);
  dst[p] = f2bf(W[(size_t)k * N + n]);
}

// ---------- gated-state recurrence; emit S3[t] = concat(s_{t-2},s_{t-1},s_t) ----------
__global__ void s3_kernel(const float* __restrict__ x, unsigned short* __restrict__ S3) {
  int tid = blockIdx.x * 256 + threadIdx.x;           // B*N*D = 24576 threads
  int b = tid / (Nn * Dd), n = (tid / Dd) % Nn, d = tid % Dd;
  auto idx = [&](int t, int k) { return ((size_t)((t * Bb + b) * Nn + n)) * 96 + k; };
  S3[idx(0, d)] = 0; S3[idx(0, 32 + d)] = 0; S3[idx(1, d)] = 0;  // s_{<0} = 0
  float s = 0.f;
  for (int t = 0; t < TO; ++t) {
    const float* xr = x + ((size_t)(b * Tt + t) * Nn + n) * Dd;
    float e = xr[1];
    s = e * xr[d] + (1.f - e) * s;
    unsigned short sb = f2bf(s);
    S3[idx(t, 64 + d)] = sb;
    if (t + 1 < TO) S3[idx(t + 1, 32 + d)] = sb;
    if (t + 2 < TO) S3[idx(t + 2, d)] = sb;
  }
}

// ---------- U' = S3 @ Wtop + b_enc ; V = S3 @ Wbot  (per (t,b): 96x96 @ 96x512) ----------
__global__ __launch_bounds__(512, 2) void uv_kernel(
    const unsigned short* __restrict__ S3, const unsigned short* __restrict__ WpE,
    const float* __restrict__ bE,
    unsigned short* __restrict__ U, unsigned short* __restrict__ V) {
  __shared__ unsigned short sS[96 * 104];     // row stride 104 elems (bank-spread)
  int tid = threadIdx.x, lane = tid & 63, w = tid >> 6;
  int tb = blockIdx.x;
  const unsigned short* s3t = S3 + (size_t)tb * (96 * 96);
  for (int c = tid; c < 96 * 12; c += 512) {
    int j = c / 12, kc = (c % 12) * 8;
    *(bf16x8*)(sS + j * 104 + kc) = *(const bf16x8*)(s3t + j * 96 + kc);
  }
  __syncthreads();
#pragma unroll
  for (int half = 0; half < 2; ++half) {
    f32x4 acc[6][4];
#pragma unroll
    for (int m = 0; m < 6; ++m)
#pragma unroll
      for (int n = 0; n < 4; ++n) acc[m][n] = f32x4{0.f, 0.f, 0.f, 0.f};
#pragma unroll
    for (int kb = 0; kb < 3; ++kb) {
      bf16x8 a[6], b[4];
#pragma unroll
      for (int m = 0; m < 6; ++m) {
        int row = 16 * m + (lane & 15);
        a[m] = *(const bf16x8*)(sS + row * 104 + kb * 32 + ((lane >> 4) << 3));
      }
#pragma unroll
      for (int n = 0; n < 4; ++n)
        b[n] = *(const bf16x8*)(WpE + ((size_t)(((half * 3 + kb) * 32 + w * 4 + n) * 64 + lane) << 3));
#pragma unroll
      for (int n = 0; n < 4; ++n)
#pragma unroll
        for (int m = 0; m < 6; ++m)
          acc[m][n] = __builtin_amdgcn_mfma_f32_16x16x32_bf16(a[m], b[n], acc[m][n], 0, 0, 0);
    }
    unsigned short* dst = half ? V : U;
#pragma unroll
    for (int n = 0; n < 4; ++n) {
      int col = 64 * w + 16 * n + (lane & 15);
      float bias = half ? 0.f : bE[col];
#pragma unroll
      for (int m = 0; m < 6; ++m)
#pragma unroll
        for (int r = 0; r < 4; ++r) {
          int row = 16 * m + ((lane >> 4) << 2) + r;
          dst[((size_t)tb * 96 + row) * 512 + col] = f2bf(acc[m][n][r] + bias);
        }
    }
  }
}

// ---------- fused MFMA layer, depth-2 B-prefetch pipeline ----------
// LDS A: row-major [96][512] bf16, byte ^= (row&7)<<4 swizzle.
template <int KB, int NFR>
DEVI void run_layer(const unsigned short* sA, const unsigned short* wp,
                    int NB, int nb0, int lane, f32x4 acc[6][NFR]) {
  const char* sab = (const char*)sA;
  const char* bb  = (const char*)wp + ((size_t)(nb0 * 64 + lane) << 4);
  const int kstride = NB << 10;
  bf16x8 bq0[NFR], bq1[NFR];
#pragma unroll
  for (int n = 0; n < NFR; ++n) bq0[n] = *(const bf16x8*)(bb + (n << 10));
#pragma unroll
  for (int n = 0; n < NFR; ++n) bq1[n] = *(const bf16x8*)(bb + kstride + (n << 10));
#pragma unroll
  for (int kb = 0; kb < KB; ++kb) {
    bf16x8 a[6];
#pragma unroll
    for (int m = 0; m < 6; ++m) {
      int row = 16 * m + (lane & 15);
      int boff = (row * 1024 + kb * 64 + ((lane >> 4) << 4)) ^ ((row & 7) << 4);
      a[m] = *(const bf16x8*)(sab + boff);
    }
#pragma unroll
    for (int n = 0; n < NFR; ++n) {
      const bf16x8 bcur = (kb & 1) ? bq1[n] : bq0[n];
#pragma unroll
      for (int m = 0; m < 6; ++m)
        acc[m][n] = __builtin_amdgcn_mfma_f32_16x16x32_bf16(a[m], bcur, acc[m][n], 0, 0, 0);
    }
    if (kb + 2 < KB) {                       // refill slot with kb+2
      const char* b2 = bb + (kb + 2) * kstride;
#pragma unroll
      for (int n = 0; n < NFR; ++n) {
        bf16x8 v = *(const bf16x8*)(b2 + (n << 10));
        if (kb & 1) bq1[n] = v; else bq0[n] = v;
      }
    }
  }
}

template <int NFR>
DEVI void zacc(f32x4 (&acc)[6][NFR]) {
#pragma unroll
  for (int m = 0; m < 6; ++m)
#pragma unroll
    for (int n = 0; n < NFR; ++n) acc[m][n] = f32x4{0.f, 0.f, 0.f, 0.f};
}

template <bool RELU>
DEVI void epilogue_to_lds(unsigned short* sA, const float* __restrict__ bias,
                          int w, int lane, f32x4 acc[6][4]) {
  float bn[4];
#pragma unroll
  for (int n = 0; n < 4; ++n) bn[n] = bias[64 * w + 16 * n + (lane & 15)];
  __syncthreads();                 // all waves done reading A
  char* sab = (char*)sA;
#pragma unroll
  for (int m = 0; m < 6; ++m)
#pragma unroll
    for (int n = 0; n < 4; ++n)
#pragma unroll
      for (int r = 0; r < 4; ++r) {
        float v = acc[m][n][r] + bn[n];
        if (RELU) v = fmaxf(v, 0.f);
        int row = 16 * m + ((lane >> 4) << 2) + r;
        int boff = (row * 1024 + (64 * w + 16 * n + (lane & 15)) * 2) ^ ((row & 7) << 4);
        *(unsigned short*)(sab + boff) = f2bf(v);
      }
  __syncthreads();                 // h visible to all waves
}

// ---------- pairwise MLP: one wg per (t,b,i); h1 = relu(U'_i + V_j) elementwise ----------
__global__ __launch_bounds__(512)
__attribute__((amdgpu_waves_per_eu(2, 2))) void pair_kernel(
    const unsigned short* __restrict__ U, const unsigned short* __restrict__ V,
    const unsigned short* __restrict__ Wp1, const float* __restrict__ b1,
    const unsigned short* __restrict__ Wp2, const float* __restrict__ b2,
    unsigned short* __restrict__ hbar) {
  __shared__ unsigned short sA[96 * 512];
  int tid = threadIdx.x, lane = tid & 63, w = tid >> 6;
  int gid = blockIdx.x;                       // (t*8+b)*96 + i
  int tb = gid / 96;
  const unsigned short* Up = U + (size_t)gid * 512;
  const unsigned short* Vp = V + (size_t)tb * (96 * 512);
  // build h1 rows j: relu(U'[i] + V[j]) -> LDS swizzled. kc fixed per thread.
  int kc = tid & 63;
  int j0 = tid >> 6;
  bf16x8 vv[12];                              // issue all V loads first (T14)
#pragma unroll
  for (int it = 0; it < 12; ++it)
    vv[it] = *(const bf16x8*)(Vp + (size_t)(j0 + it * 8) * 512 + kc * 8);
  float u[8];
  {
    bf16x8 u8 = *(const bf16x8*)(Up + kc * 8);
#pragma unroll
    for (int l = 0; l < 8; ++l) u[l] = bf2f(((const unsigned short*)&u8)[l]);
  }
#pragma unroll
  for (int it = 0; it < 12; ++it) {
    int j = j0 + it * 8;
    unsigned short h[8];
#pragma unroll
    for (int l = 0; l < 8; ++l)
      h[l] = f2bf(fmaxf(u[l] + bf2f(((const unsigned short*)&vv[it])[l]), 0.f));
    int boff = (j * 1024 + kc * 16) ^ ((j & 7) << 4);
    *(bf16x8*)((char*)sA + boff) = *(bf16x8*)h;
  }
  __syncthreads();
  f32x4 acc[6][4];
  zacc(acc); run_layer<16, 4>(sA, Wp1, 32, w * 4, lane, acc);
  epilogue_to_lds<true>(sA, b1, w, lane, acc);
  zacc(acc); run_layer<16, 4>(sA, Wp2, 32, w * 4, lane, acc);
  // bias + relu + mean over the 96 j-rows (wg owns all of them -> no atomics)
  float p[4];
#pragma unroll
  for (int n = 0; n < 4; ++n) {
    float bn = b2[64 * w + 16 * n + (lane & 15)];
    float s = 0.f;
#pragma unroll
    for (int m = 0; m < 6; ++m)
#pragma unroll
      for (int r = 0; r < 4; ++r) s += fmaxf(acc[m][n][r] + bn, 0.f);
    p[n] = s;
  }
#pragma unroll
  for (int n = 0; n < 4; ++n) {
    p[n] += __shfl_xor(p[n], 16);
    p[n] += __shfl_xor(p[n], 32);
  }
  int g = lane >> 4;
  float sel = g == 0 ? p[0] : g == 1 ? p[1] : g == 2 ? p[2] : p[3];
  hbar[(size_t)gid * 512 + 64 * w + lane] = f2bf(sel * (1.f / 96.f));
}

// ---------- decode: emb = hbar@W3+b3 ; h = relu(emb@Wd1+bd1) ; out = h@Wd2+bd2 ----------
__global__ __launch_bounds__(512)
__attribute__((amdgpu_waves_per_eu(2, 2))) void decode_kernel(
    const unsigned short* __restrict__ hbar,
    const unsigned short* __restrict__ Wp3, const float* __restrict__ b3,
    const unsigned short* __restrict__ WpD1, const float* __restrict__ bd1,
    const unsigned short* __restrict__ WpD2, const float* __restrict__ bd2,
    float* __restrict__ out) {
  __shared__ unsigned short sA[96 * 512];
  int tid = threadIdx.x, lane = tid & 63, w = tid >> 6;
  int r0 = blockIdx.x * 96;
  for (int c = tid; c < 96 * 64; c += 512) {
    int j = c / 64, kc = (c % 64) * 8;
    bf16x8 v = *(const bf16x8*)(hbar + (size_t)(r0 + j) * 512 + kc);
    int boff = (j * 1024 + kc * 2) ^ ((j & 7) << 4);
    *(bf16x8*)((char*)sA + boff) = v;
  }
  __syncthreads();
  f32x4 acc[6][4];
  zacc(acc); run_layer<16, 4>(sA, Wp3, 32, w * 4, lane, acc);
  epilogue_to_lds<false>(sA, b3, w, lane, acc);   // emb: linear, no relu
  zacc(acc); run_layer<16, 4>(sA, WpD1, 32, w * 4, lane, acc);
  epilogue_to_lds<true>(sA, bd1, w, lane, acc);
  if (w == 0) {                                   // final 512->32: wave 0 only
    f32x4 acc2[6][2];
    zacc(acc2); run_layer<16, 2>(sA, WpD2, 2, 0, lane, acc2);
#pragma unroll
    for (int n = 0; n < 2; ++n) {
      float bn = bd2[16 * n + (lane & 15)];
#pragma unroll
      for (int m = 0; m < 6; ++m)
#pragma unroll
        for (int r = 0; r < 4; ++r) {
          int row = 16 * m + ((lane >> 4) << 2) + r;
          int R = r0 + row;                       // (t*8+b)*96+i
          int t = R / 768, b = (R / 96) & 7, i = R % 96;
          out[(((size_t)b * TO + t) * 96 + i) * 32 + 16 * n + (lane & 15)] =
              acc2[m][n][r] + bn;
        }
    }
  }
}

extern "C" void kernel_launch(void* const* d_in, const int* in_sizes, int n_in,
                              void* d_out, int out_size, void* d_ws, size_t ws_size,
                              hipStream_t stream) {
  const float* x     = (const float*)d_in[0];
  const float* W_enc = (const float*)d_in[1];
  const float* b_enc = (const float*)d_in[2];
  const float* W1    = (const float*)d_in[3];
  const float* b1    = (const float*)d_in[4];
  const float* W2    = (const float*)d_in[5];
  const float* b2    = (const float*)d_in[6];
  const float* W3    = (const float*)d_in[7];
  const float* b3    = (const float*)d_in[8];
  const float* Wd1   = (const float*)d_in[9];
  const float* bd1   = (const float*)d_in[10];
  const float* Wd2   = (const float*)d_in[11];
  const float* bd2   = (const float*)d_in[12];
  float* out = (float*)d_out;

  char* ws = (char*)d_ws;
  size_t off = 0;
  auto alloc = [&](size_t bytes) {
    char* p = ws + off;
    off += (bytes + 255) & ~(size_t)255;
    return p;
  };
  unsigned short* S3    = (unsigned short*)alloc((size_t)TB * 96 * 96 * 2);    // 3.4 MB
  unsigned short* Ub    = (unsigned short*)alloc((size_t)ROWS * 512 * 2);      // 18.1 MB
  unsigned short* Vb    = (unsigned short*)alloc((size_t)ROWS * 512 * 2);      // 18.1 MB
  unsigned short* hbar  = (unsigned short*)alloc((size_t)ROWS * 512 * 2);      // 18.1 MB
  unsigned short* WpE   = (unsigned short*)alloc((size_t)192 * 512 * 2);
  unsigned short* Wp1p  = (unsigned short*)alloc((size_t)512 * 512 * 2);
  unsigned short* Wp2p  = (unsigned short*)alloc((size_t)512 * 512 * 2);
  unsigned short* Wp3p  = (unsigned short*)alloc((size_t)512 * 512 * 2);
  unsigned short* WpD1p = (unsigned short*)alloc((size_t)512 * 512 * 2);
  unsigned short* WpD2p = (unsigned short*)alloc((size_t)512 * 32 * 2);

  pack_kernel<<<(192 * 512) / 256, 256, 0, stream>>>(W_enc, WpE, 192, 512);
  pack_kernel<<<(512 * 512) / 256, 256, 0, stream>>>(W1, Wp1p, 512, 512);
  pack_kernel<<<(512 * 512) / 256, 256, 0, stream>>>(W2, Wp2p, 512, 512);
  pack_kernel<<<(512 * 512) / 256, 256, 0, stream>>>(W3, Wp3p, 512, 512);
  pack_kernel<<<(512 * 512) / 256, 256, 0, stream>>>(Wd1, WpD1p, 512, 512);
  pack_kernel<<<(512 * 32) / 256, 256, 0, stream>>>(Wd2, WpD2p, 512, 32);
  s3_kernel<<<96, 256, 0, stream>>>(x, S3);
  uv_kernel<<<TB, 512, 0, stream>>>(S3, WpE, b_enc, Ub, Vb);
  pair_kernel<<<ROWS, 512, 0, stream>>>(Ub, Vb, Wp1p, b1, Wp2p, b2, hbar);
  decode_kernel<<<TB, 512, 0, stream>>>(hbar, Wp3p, b3, WpD1p, bd1, WpD2p, bd2, out);
  (void)in_sizes; (void)n_in; (void)out_size; (void)ws_size;
}

// Round 4
// 1544.949 us; speedup vs baseline: 1.0458x; 1.0458x over previous
//
#include <hip/hip_runtime.h>

#define DEVI __device__ __forceinline__

typedef __bf16 bf16x8 __attribute__((ext_vector_type(8)));
typedef float  f32x4  __attribute__((ext_vector_type(4)));

static constexpr int Bb = 8, Tt = 24, Nn = 96, Dd = 32;
static constexpr int TO = 23;                 // output timesteps (outs[:-1])
static constexpr int TB = TO * Bb;            // 184 (t,b) groups
static constexpr int ROWS = TB * Nn;          // 17664 (t,b,i) rows

DEVI unsigned short f2bf(float f) {
  union { float f; unsigned u; } v; v.f = f;
  unsigned r = v.u + 0x7FFFu + ((v.u >> 16) & 1u);  // RNE
  return (unsigned short)(r >> 16);
}
DEVI float bf2f(unsigned short u) {
  union { unsigned u; float f; } v; v.u = (unsigned)u << 16; return v.f;
}

// ---------- pack f32 weights -> bf16 MFMA B-fragment layout ----------
// dst[((kb*NB+nb)*64+lane)*8+j] = W[kb*32+(lane>>4)*8+j][nb*16+(lane&15)]
__global__ void pack_kernel(const float* __restrict__ W, unsigned short* __restrict__ dst,
                            int K, int N) {
  int p = blockIdx.x * 256 + threadIdx.x;
  if (p >= K * N) return;
  int j = p & 7, lane = (p >> 3) & 63, pb = p >> 9;
  int NB = N >> 4;
  int nb = pb % NB, kb = pb / NB;
  int k = kb * 32 + ((lane >> 4) << 3) + j;
  int n = nb * 16 + (lane & 15);
  dst[p] = f2bf(W[(size_t)k * N + n]);
}

// ---------- gated-state recurrence; emit S3[t] = concat(s_{t-2},s_{t-1},s_t) ----------
__global__ void s3_kernel(const float* __restrict__ x, unsigned short* __restrict__ S3) {
  int tid = blockIdx.x * 256 + threadIdx.x;           // B*N*D = 24576 threads
  int b = tid / (Nn * Dd), n = (tid / Dd) % Nn, d = tid % Dd;
  auto idx = [&](int t, int k) { return ((size_t)((t * Bb + b) * Nn + n)) * 96 + k; };
  S3[idx(0, d)] = 0; S3[idx(0, 32 + d)] = 0; S3[idx(1, d)] = 0;  // s_{<0} = 0
  float s = 0.f;
  for (int t = 0; t < TO; ++t) {
    const float* xr = x + ((size_t)(b * Tt + t) * Nn + n) * Dd;
    float e = xr[1];
    s = e * xr[d] + (1.f - e) * s;
    unsigned short sb = f2bf(s);
    S3[idx(t, 64 + d)] = sb;
    if (t + 1 < TO) S3[idx(t + 1, 32 + d)] = sb;
    if (t + 2 < TO) S3[idx(t + 2, d)] = sb;
  }
}

// ---------- U' = S3 @ Wtop + b_enc ; V = S3 @ Wbot  (per (t,b): 96x96 @ 96x512) ----------
__global__ __launch_bounds__(512, 2) void uv_kernel(
    const unsigned short* __restrict__ S3, const unsigned short* __restrict__ WpE,
    const float* __restrict__ bE,
    unsigned short* __restrict__ U, unsigned short* __restrict__ V) {
  __shared__ unsigned short sS[96 * 104];     // row stride 104 elems (bank-spread)
  int tid = threadIdx.x, lane = tid & 63, w = tid >> 6;
  int tb = blockIdx.x;
  const unsigned short* s3t = S3 + (size_t)tb * (96 * 96);
  for (int c = tid; c < 96 * 12; c += 512) {
    int j = c / 12, kc = (c % 12) * 8;
    *(bf16x8*)(sS + j * 104 + kc) = *(const bf16x8*)(s3t + j * 96 + kc);
  }
  __syncthreads();
#pragma unroll
  for (int half = 0; half < 2; ++half) {
    f32x4 acc[6][4];
#pragma unroll
    for (int m = 0; m < 6; ++m)
#pragma unroll
      for (int n = 0; n < 4; ++n) acc[m][n] = f32x4{0.f, 0.f, 0.f, 0.f};
#pragma unroll
    for (int kb = 0; kb < 3; ++kb) {
      bf16x8 a[6], b[4];
#pragma unroll
      for (int m = 0; m < 6; ++m) {
        int row = 16 * m + (lane & 15);
        a[m] = *(const bf16x8*)(sS + row * 104 + kb * 32 + ((lane >> 4) << 3));
      }
#pragma unroll
      for (int n = 0; n < 4; ++n)
        b[n] = *(const bf16x8*)(WpE + ((size_t)(((half * 3 + kb) * 32 + w * 4 + n) * 64 + lane) << 3));
#pragma unroll
      for (int n = 0; n < 4; ++n)
#pragma unroll
        for (int m = 0; m < 6; ++m)
          acc[m][n] = __builtin_amdgcn_mfma_f32_16x16x32_bf16(a[m], b[n], acc[m][n], 0, 0, 0);
    }
    unsigned short* dst = half ? V : U;
#pragma unroll
    for (int n = 0; n < 4; ++n) {
      int col = 64 * w + 16 * n + (lane & 15);
      float bias = half ? 0.f : bE[col];
#pragma unroll
      for (int m = 0; m < 6; ++m)
#pragma unroll
        for (int r = 0; r < 4; ++r) {
          int row = 16 * m + ((lane >> 4) << 2) + r;
          dst[((size_t)tb * 96 + row) * 512 + col] = f2bf(acc[m][n][r] + bias);
        }
    }
  }
}

// ---------- fused MFMA layer: depth-3 B-prefetch + per-wg K-phase stagger ----------
// LDS A: row-major [96][512] bf16, byte ^= (row&7)<<4 swizzle.
template <int KB, int NFR>
DEVI void run_layer(const unsigned short* sA, const unsigned short* wp,
                    int NB, int nb0, int lane, int phase, f32x4 acc[6][NFR]) {
  const char* sab = (const char*)sA;
  const char* bb  = (const char*)wp + ((size_t)(nb0 * 64 + lane) << 4);
  const int kstride = NB << 10;
  bf16x8 bq[3][NFR];
#pragma unroll
  for (int d = 0; d < 3; ++d)
#pragma unroll
    for (int n = 0; n < NFR; ++n)
      bq[d][n] = *(const bf16x8*)(bb + ((phase + d) & (KB - 1)) * kstride + (n << 10));
#pragma unroll
  for (int kb = 0; kb < KB; ++kb) {
    const int slot = kb % 3;                  // compile-time under full unroll
    int kbp = (kb + phase) & (KB - 1);
    bf16x8 a[6];
#pragma unroll
    for (int m = 0; m < 6; ++m) {
      int row = 16 * m + (lane & 15);
      int boff = (row * 1024 + kbp * 64 + ((lane >> 4) << 4)) ^ ((row & 7) << 4);
      a[m] = *(const bf16x8*)(sab + boff);
    }
#pragma unroll
    for (int n = 0; n < NFR; ++n)
#pragma unroll
      for (int m = 0; m < 6; ++m)
        acc[m][n] = __builtin_amdgcn_mfma_f32_16x16x32_bf16(a[m], bq[slot][n], acc[m][n], 0, 0, 0);
    if (kb + 3 < KB) {                        // refill just-consumed slot with kb+3
      int kbn = (kb + 3 + phase) & (KB - 1);
      const char* b2 = bb + kbn * kstride;
#pragma unroll
      for (int n = 0; n < NFR; ++n)
        bq[slot][n] = *(const bf16x8*)(b2 + (n << 10));
    }
  }
}

template <int NFR>
DEVI void zacc(f32x4 (&acc)[6][NFR]) {
#pragma unroll
  for (int m = 0; m < 6; ++m)
#pragma unroll
    for (int n = 0; n < NFR; ++n) acc[m][n] = f32x4{0.f, 0.f, 0.f, 0.f};
}

template <bool RELU>
DEVI void epilogue_to_lds(unsigned short* sA, const float* __restrict__ bias,
                          int w, int lane, f32x4 acc[6][4]) {
  float bn[4];
#pragma unroll
  for (int n = 0; n < 4; ++n) bn[n] = bias[64 * w + 16 * n + (lane & 15)];
  __syncthreads();                 // all waves done reading A
  char* sab = (char*)sA;
#pragma unroll
  for (int m = 0; m < 6; ++m)
#pragma unroll
    for (int n = 0; n < 4; ++n)
#pragma unroll
      for (int r = 0; r < 4; ++r) {
        float v = acc[m][n][r] + bn[n];
        if (RELU) v = fmaxf(v, 0.f);
        int row = 16 * m + ((lane >> 4) << 2) + r;
        int boff = (row * 1024 + (64 * w + 16 * n + (lane & 15)) * 2) ^ ((row & 7) << 4);
        *(unsigned short*)(sab + boff) = f2bf(v);
      }
  __syncthreads();                 // h visible to all waves
}

// ---------- pairwise MLP: one wg per (t,b,i); h1 = relu(U'_i + V_j) elementwise ----------
__global__ __launch_bounds__(512)
__attribute__((amdgpu_waves_per_eu(2, 2))) void pair_kernel(
    const unsigned short* __restrict__ U, const unsigned short* __restrict__ V,
    const unsigned short* __restrict__ Wp1, const float* __restrict__ b1,
    const unsigned short* __restrict__ Wp2, const float* __restrict__ b2,
    unsigned short* __restrict__ hbar) {
  __shared__ unsigned short sA[96 * 512];
  int tid = threadIdx.x, lane = tid & 63, w = tid >> 6;
  int gid = blockIdx.x;                       // (t*8+b)*96 + i
  int tb = gid / 96;
  int phase = gid & 15;                       // L2 bank-spread stagger
  const unsigned short* Up = U + (size_t)gid * 512;
  const unsigned short* Vp = V + (size_t)tb * (96 * 512);
  // build h1 rows j: relu(U'[i] + V[j]) -> LDS swizzled. kc fixed per thread.
  int kc = tid & 63;
  int j0 = tid >> 6;
  float u[8];
  {
    bf16x8 u8 = *(const bf16x8*)(Up + kc * 8);
#pragma unroll
    for (int l = 0; l < 8; ++l) u[l] = bf2f(((const unsigned short*)&u8)[l]);
  }
#pragma unroll
  for (int half = 0; half < 2; ++half) {
    bf16x8 vv[6];                             // batched issue (T14), capped pressure
#pragma unroll
    for (int it = 0; it < 6; ++it)
      vv[it] = *(const bf16x8*)(Vp + (size_t)(j0 + (half * 6 + it) * 8) * 512 + kc * 8);
#pragma unroll
    for (int it = 0; it < 6; ++it) {
      int j = j0 + (half * 6 + it) * 8;
      unsigned short h[8];
#pragma unroll
      for (int l = 0; l < 8; ++l)
        h[l] = f2bf(fmaxf(u[l] + bf2f(((const unsigned short*)&vv[it])[l]), 0.f));
      int boff = (j * 1024 + kc * 16) ^ ((j & 7) << 4);
      *(bf16x8*)((char*)sA + boff) = *(bf16x8*)h;
    }
  }
  __syncthreads();
  f32x4 acc[6][4];
  zacc(acc); run_layer<16, 4>(sA, Wp1, 32, w * 4, lane, phase, acc);
  epilogue_to_lds<true>(sA, b1, w, lane, acc);
  zacc(acc); run_layer<16, 4>(sA, Wp2, 32, w * 4, lane, phase, acc);
  // bias + relu + mean over the 96 j-rows (wg owns all of them -> no atomics)
  float p[4];
#pragma unroll
  for (int n = 0; n < 4; ++n) {
    float bn = b2[64 * w + 16 * n + (lane & 15)];
    float s = 0.f;
#pragma unroll
    for (int m = 0; m < 6; ++m)
#pragma unroll
      for (int r = 0; r < 4; ++r) s += fmaxf(acc[m][n][r] + bn, 0.f);
    p[n] = s;
  }
#pragma unroll
  for (int n = 0; n < 4; ++n) {
    p[n] += __shfl_xor(p[n], 16);
    p[n] += __shfl_xor(p[n], 32);
  }
  int g = lane >> 4;
  float sel = g == 0 ? p[0] : g == 1 ? p[1] : g == 2 ? p[2] : p[3];
  hbar[(size_t)gid * 512 + 64 * w + lane] = f2bf(sel * (1.f / 96.f));
}

// ---------- decode: emb = hbar@W3+b3 ; h = relu(emb@Wd1+bd1) ; out = h@Wd2+bd2 ----------
__global__ __launch_bounds__(512)
__attribute__((amdgpu_waves_per_eu(2, 2))) void decode_kernel(
    const unsigned short* __restrict__ hbar,
    const unsigned short* __restrict__ Wp3, const float* __restrict__ b3,
    const unsigned short* __restrict__ WpD1, const float* __restrict__ bd1,
    const unsigned short* __restrict__ WpD2, const float* __restrict__ bd2,
    float* __restrict__ out) {
  __shared__ unsigned short sA[96 * 512];
  int tid = threadIdx.x, lane = tid & 63, w = tid >> 6;
  int r0 = blockIdx.x * 96;
  int phase = blockIdx.x & 15;
  for (int c = tid; c < 96 * 64; c += 512) {
    int j = c / 64, kc = (c % 64) * 8;
    bf16x8 v = *(const bf16x8*)(hbar + (size_t)(r0 + j) * 512 + kc);
    int boff = (j * 1024 + kc * 2) ^ ((j & 7) << 4);
    *(bf16x8*)((char*)sA + boff) = v;
  }
  __syncthreads();
  f32x4 acc[6][4];
  zacc(acc); run_layer<16, 4>(sA, Wp3, 32, w * 4, lane, phase, acc);
  epilogue_to_lds<false>(sA, b3, w, lane, acc);   // emb: linear, no relu
  zacc(acc); run_layer<16, 4>(sA, WpD1, 32, w * 4, lane, phase, acc);
  epilogue_to_lds<true>(sA, bd1, w, lane, acc);
  if (w == 0) {                                   // final 512->32: wave 0 only
    f32x4 acc2[6][2];
    zacc(acc2); run_layer<16, 2>(sA, WpD2, 2, 0, lane, phase, acc2);
#pragma unroll
    for (int n = 0; n < 2; ++n) {
      float bn = bd2[16 * n + (lane & 15)];
#pragma unroll
      for (int m = 0; m < 6; ++m)
#pragma unroll
        for (int r = 0; r < 4; ++r) {
          int row = 16 * m + ((lane >> 4) << 2) + r;
          int R = r0 + row;                       // (t*8+b)*96+i
          int t = R / 768, b = (R / 96) & 7, i = R % 96;
          out[(((size_t)b * TO + t) * 96 + i) * 32 + 16 * n + (lane & 15)] =
              acc2[m][n][r] + bn;
        }
    }
  }
}

extern "C" void kernel_launch(void* const* d_in, const int* in_sizes, int n_in,
                              void* d_out, int out_size, void* d_ws, size_t ws_size,
                              hipStream_t stream) {
  const float* x     = (const float*)d_in[0];
  const float* W_enc = (const float*)d_in[1];
  const float* b_enc = (const float*)d_in[2];
  const float* W1    = (const float*)d_in[3];
  const float* b1    = (const float*)d_in[4];
  const float* W2    = (const float*)d_in[5];
  const float* b2    = (const float*)d_in[6];
  const float* W3    = (const float*)d_in[7];
  const float* b3    = (const float*)d_in[8];
  const float* Wd1   = (const float*)d_in[9];
  const float* bd1   = (const float*)d_in[10];
  const float* Wd2   = (const float*)d_in[11];
  const float* bd2   = (const float*)d_in[12];
  float* out = (float*)d_out;

  char* ws = (char*)d_ws;
  size_t off = 0;
  auto alloc = [&](size_t bytes) {
    char* p = ws + off;
    off += (bytes + 255) & ~(size_t)255;
    return p;
  };
  unsigned short* S3    = (unsigned short*)alloc((size_t)TB * 96 * 96 * 2);    // 3.4 MB
  unsigned short* Ub    = (unsigned short*)alloc((size_t)ROWS * 512 * 2);      // 18.1 MB
  unsigned short* Vb    = (unsigned short*)alloc((size_t)ROWS * 512 * 2);      // 18.1 MB
  unsigned short* hbar  = (unsigned short*)alloc((size_t)ROWS * 512 * 2);      // 18.1 MB
  unsigned short* WpE   = (unsigned short*)alloc((size_t)192 * 512 * 2);
  unsigned short* Wp1p  = (unsigned short*)alloc((size_t)512 * 512 * 2);
  unsigned short* Wp2p  = (unsigned short*)alloc((size_t)512 * 512 * 2);
  unsigned short* Wp3p  = (unsigned short*)alloc((size_t)512 * 512 * 2);
  unsigned short* WpD1p = (unsigned short*)alloc((size_t)512 * 512 * 2);
  unsigned short* WpD2p = (unsigned short*)alloc((size_t)512 * 32 * 2);

  pack_kernel<<<(192 * 512) / 256, 256, 0, stream>>>(W_enc, WpE, 192, 512);
  pack_kernel<<<(512 * 512) / 256, 256, 0, stream>>>(W1, Wp1p, 512, 512);
  pack_kernel<<<(512 * 512) / 256, 256, 0, stream>>>(W2, Wp2p, 512, 512);
  pack_kernel<<<(512 * 512) / 256, 256, 0, stream>>>(W3, Wp3p, 512, 512);
  pack_kernel<<<(512 * 512) / 256, 256, 0, stream>>>(Wd1, WpD1p, 512, 512);
  pack_kernel<<<(512 * 32) / 256, 256, 0, stream>>>(Wd2, WpD2p, 512, 32);
  s3_kernel<<<96, 256, 0, stream>>>(x, S3);
  uv_kernel<<<TB, 512, 0, stream>>>(S3, WpE, b_enc, Ub, Vb);
  pair_kernel<<<ROWS, 512, 0, stream>>>(Ub, Vb, Wp1p, b1, Wp2p, b2, hbar);
  decode_kernel<<<TB, 512, 0, stream>>>(hbar, Wp3p, b3, WpD1p, bd1, WpD2p, bd2, out);
  (void)in_sizes; (void)n_in; (void)out_size; (void)ws_size;
}